// Round 5
// baseline (288.705 us; speedup 1.0000x reference)
//
#include <hip/hip_runtime.h>

// FractalEmbedding: out[b,l,d] = scale * sum_f feats(token)[f] * W[d,f]
// feats = 8-step Julia iteration on c_table[token], interleaved (zr,zi).
//
// B=8, L=8192 -> 65536 tokens; D=1024; 16 features. Output = 268 MB f32.
// Evidence so far: fillBuffer sustains 6.6 TB/s at 3 waves/CU (pure wide
// stores); our looped kernels plateau ~106 us (~2.5 TB/s) regardless of
// load pipelining (R3) or packed math (R4). Remaining suspect: per-iteration
// store->register-reuse serialization — each loop iteration overwrites the
// acc registers the previous iteration's stores read, forcing a vmcnt wait
// (store-data consumption, hundreds of cycles) inside every iteration.
//
// v5: NO LOOP. One token-group (8 tokens) per block; compute into 8 distinct
// acc registers, fire 8 stores, end the wave. Stores drain after s_endpgm
// while the CU launches the next block — store latency off the critical path,
// hidden by block churn (8192 independent blocks).
//   * BLOCK=512, thread t -> output dims 2t,2t+1 (w2 = 32 VGPRs, scale folded)
//   * token ids + c values wave-uniform broadcast loads
//   * Julia packed 2 tokens per v2f chain (4 chains), fused ascending-order
//     dot accumulation (same FMA order as the passing v4 -> bit-identical)

#define STEPS 8
#define NFEAT (2 * STEPS)
#define EMBED 1024
#define NTOK (8 * 8192)
#define TB 8                     // tokens per block
#define BLOCK 512                // thread t -> dims 2t, 2t+1
#define GRID (NTOK / TB)         // 8192 blocks, exact

typedef float v2f __attribute__((ext_vector_type(2)));

__global__ __launch_bounds__(BLOCK) void FractalEmbedding_30365418782757_kernel(
    const int* __restrict__ tok,
    const float* __restrict__ ctab,   // (V, 2)
    const float* __restrict__ W,      // (1024, 16) row-major
    const float* __restrict__ scale_p,
    float* __restrict__ out)          // (NTOK, 1024)
{
    const int t = threadIdx.x;
    const float s = *scale_p;

    const int4*   tok4 = reinterpret_cast<const int4*>(tok);
    const float2* c2   = reinterpret_cast<const float2*>(ctab);
    const int     b    = blockIdx.x;

    // Issue the uniform token-id loads first (latency hides under W preamble).
    int4 idsA = tok4[2 * b];
    int4 idsB = tok4[2 * b + 1];

    // Two W rows per thread, pair-interleaved for packed FMA; scale folded.
    v2f w2[NFEAT];                    // w2[k] = { W[2t][k], W[2t+1][k] } * s
    {
        const float4* r0 = reinterpret_cast<const float4*>(W + (size_t)(2 * t)     * NFEAT);
        const float4* r1 = reinterpret_cast<const float4*>(W + (size_t)(2 * t + 1) * NFEAT);
#pragma unroll
        for (int q = 0; q < 4; ++q) {
            float4 a = r0[q];
            float4 c = r1[q];
            w2[4 * q + 0] = (v2f){a.x * s, c.x * s};
            w2[4 * q + 1] = (v2f){a.y * s, c.y * s};
            w2[4 * q + 2] = (v2f){a.z * s, c.z * s};
            w2[4 * q + 3] = (v2f){a.w * s, c.w * s};
        }
    }

    // 8 uniform (broadcast) c loads.
    float2 c0 = c2[idsA.x], c1 = c2[idsA.y], c2_ = c2[idsA.z], c3 = c2[idsA.w];
    float2 c4 = c2[idsB.x], c5 = c2[idsB.y], c6  = c2[idsB.z], c7 = c2[idsB.w];

    // 4 packed Julia chains: tokens (0,1) (2,3) (4,5) (6,7).
    v2f cx01 = (v2f){c0.x, c1.x}, cy01 = (v2f){c0.y, c1.y};
    v2f cx23 = (v2f){c2_.x, c3.x}, cy23 = (v2f){c2_.y, c3.y};
    v2f cx45 = (v2f){c4.x, c5.x}, cy45 = (v2f){c4.y, c5.y};
    v2f cx67 = (v2f){c6.x, c7.x}, cy67 = (v2f){c6.y, c7.y};
    v2f z = (v2f){0.f, 0.f};
    v2f zr01 = z, zi01 = z, zr23 = z, zi23 = z;
    v2f zr45 = z, zi45 = z, zr67 = z, zi67 = z;
    v2f a0 = z, a1 = z, a2 = z, a3 = z, a4 = z, a5 = z, a6 = z, a7 = z;

#pragma unroll
    for (int st = 0; st < STEPS; ++st) {
        v2f na01 = zr01 * zr01 - zi01 * zi01 + cx01;
        v2f nb01 = 2.0f * zr01 * zi01 + cy01;
        v2f na23 = zr23 * zr23 - zi23 * zi23 + cx23;
        v2f nb23 = 2.0f * zr23 * zi23 + cy23;
        v2f na45 = zr45 * zr45 - zi45 * zi45 + cx45;
        v2f nb45 = 2.0f * zr45 * zi45 + cy45;
        v2f na67 = zr67 * zr67 - zi67 * zi67 + cx67;
        v2f nb67 = 2.0f * zr67 * zi67 + cy67;
        zr01 = na01; zi01 = nb01; zr23 = na23; zi23 = nb23;
        zr45 = na45; zi45 = nb45; zr67 = na67; zi67 = nb67;
        // ascending-feature accumulation, same order as reference dot loop
        v2f wr = w2[2 * st], wi = w2[2 * st + 1];
        a0 += zr01.x * wr; a0 += zi01.x * wi;
        a1 += zr01.y * wr; a1 += zi01.y * wi;
        a2 += zr23.x * wr; a2 += zi23.x * wi;
        a3 += zr23.y * wr; a3 += zi23.y * wi;
        a4 += zr45.x * wr; a4 += zi45.x * wi;
        a5 += zr45.y * wr; a5 += zi45.y * wi;
        a6 += zr67.x * wr; a6 += zi67.x * wi;
        a7 += zr67.y * wr; a7 += zi67.y * wi;
    }

    // 8 token rows, 8 B/lane contiguous (512 B per wave-store), then exit.
    v2f* obase = reinterpret_cast<v2f*>(out + (size_t)(TB * b) * EMBED) + t;
    obase[0 * (EMBED / 2)] = a0;
    obase[1 * (EMBED / 2)] = a1;
    obase[2 * (EMBED / 2)] = a2;
    obase[3 * (EMBED / 2)] = a3;
    obase[4 * (EMBED / 2)] = a4;
    obase[5 * (EMBED / 2)] = a5;
    obase[6 * (EMBED / 2)] = a6;
    obase[7 * (EMBED / 2)] = a7;
}

extern "C" void kernel_launch(void* const* d_in, const int* in_sizes, int n_in,
                              void* d_out, int out_size, void* d_ws, size_t ws_size,
                              hipStream_t stream) {
    const int*   tok   = (const int*)d_in[0];
    const float* ctab  = (const float*)d_in[1];
    const float* W     = (const float*)d_in[2];
    const float* scale = (const float*)d_in[3];
    float*       out   = (float*)d_out;

    FractalEmbedding_30365418782757_kernel<<<GRID, BLOCK, 0, stream>>>(tok, ctab, W, scale, out);
}

// Round 7
// 271.851 us; speedup vs baseline: 1.0620x; 1.0620x over previous
//
#include <hip/hip_runtime.h>

// FractalEmbedding: out[b,l,d] = scale * sum_f feats(token)[f] * W[d,f]
// feats = 8-step Julia iteration on c_table[token], interleaved (zr,zi).
//
// B=8, L=8192 -> 65536 tokens; D=1024; 16 features. Output = 268 MB f32.
// Store-BW floor ~42 us (fill kernel: 6.6 TB/s on this machine). Previous
// versions plateaued at ~106 us because EVERY wave covering a token
// recomputed that token's Julia chain (~48 instr) before its dot-slice:
// 640 wave-instr/token -> ~45 us of chip-wide VALU issue fighting the
// store stream. v5 (no-loop) showed store latency is NOT the issue.
//
// v6: compute each token's features ONCE, share via LDS.
//   phase 1: lane i of wave 0 computes token i's 16 feats (48 instr for the
//            whole 64-token block), writes 64 B to LDS (4 KB total).
//   phase 2: all 4 waves loop 64 tokens: 4 broadcast ds_read_b128 (same
//            address across lanes -> conflict-free) + 64 FMAs + 1 dwordx4
//            store. ~280 wave-instr/token total: VALU ~16 us << 42 us BW
//            floor -> store-bound.
// Grid 1024 x 256 (64 tokens/block, exact). W rows in registers (64 VGPR),
// scale folded (scale==1.0 -> bit-identical). FMA order per output dim
// identical to the passing v4 (ascending features).

#define STEPS 8
#define NFEAT (2 * STEPS)
#define EMBED 1024
#define NTOK (8 * 8192)
#define TOKB 64                  // tokens per block
#define BLOCK 256                // thread t -> output dims 4t..4t+3
#define GRID (NTOK / TOKB)       // 1024 blocks, exact

typedef float v4f __attribute__((ext_vector_type(4)));

__global__ __launch_bounds__(BLOCK) void FractalEmbedding_30365418782757_kernel(
    const int* __restrict__ tok,
    const float* __restrict__ ctab,   // (V, 2)
    const float* __restrict__ W,      // (1024, 16) row-major
    const float* __restrict__ scale_p,
    float* __restrict__ out)          // (NTOK, 1024)
{
    __shared__ float feats_lds[TOKB * NFEAT];   // 4 KB

    const int t  = threadIdx.x;
    const int g0 = blockIdx.x * TOKB;           // first token of this block
    const float s = *scale_p;

    // ---- phase 1: wave 0 computes all 64 tokens' features, one per lane ----
    if (t < TOKB) {
        const int id = tok[g0 + t];                               // coalesced
        const float2 c = reinterpret_cast<const float2*>(ctab)[id]; // gather
        float f[NFEAT];
        float zr = 0.0f, zi = 0.0f;
#pragma unroll
        for (int st = 0; st < STEPS; ++st) {
            float nzr = zr * zr - zi * zi + c.x;
            float nzi = 2.0f * zr * zi + c.y;
            zr = nzr; zi = nzi;
            f[2 * st]     = zr;
            f[2 * st + 1] = zi;
        }
        v4f* dst = reinterpret_cast<v4f*>(feats_lds + t * NFEAT);
#pragma unroll
        for (int q = 0; q < 4; ++q)
            dst[q] = (v4f){f[4 * q], f[4 * q + 1], f[4 * q + 2], f[4 * q + 3]};
    }

    // W rows for dims 4t..4t+3 into registers while phase 1 runs elsewhere.
    float w[4][NFEAT];
#pragma unroll
    for (int r = 0; r < 4; ++r) {
        const float4* wrow = reinterpret_cast<const float4*>(W + (size_t)(4 * t + r) * NFEAT);
#pragma unroll
        for (int q = 0; q < 4; ++q) {
            float4 v = wrow[q];
            w[r][4 * q + 0] = v.x * s;
            w[r][4 * q + 1] = v.y * s;
            w[r][4 * q + 2] = v.z * s;
            w[r][4 * q + 3] = v.w * s;
        }
    }

    __syncthreads();

    // ---- phase 2: pure dot + store, 64 tokens, all waves ----
    const v4f* fp = reinterpret_cast<const v4f*>(feats_lds);
    v4f* obase = reinterpret_cast<v4f*>(out + (size_t)g0 * EMBED) + t;

#pragma unroll 2
    for (int tk = 0; tk < TOKB; ++tk) {
        // 4 broadcast LDS reads: 16 features of token tk.
        v4f f0 = fp[tk * 4 + 0];
        v4f f1 = fp[tk * 4 + 1];
        v4f f2 = fp[tk * 4 + 2];
        v4f f3 = fp[tk * 4 + 3];
        float fk[NFEAT] = {f0.x, f0.y, f0.z, f0.w,  f1.x, f1.y, f1.z, f1.w,
                           f2.x, f2.y, f2.z, f2.w,  f3.x, f3.y, f3.z, f3.w};

        float acc[4];
#pragma unroll
        for (int r = 0; r < 4; ++r) {
            float a = 0.0f;
#pragma unroll
            for (int k = 0; k < NFEAT; ++k) a += fk[k] * w[r][k];  // ascending
            acc[r] = a;
        }
        v4f o = (v4f){acc[0], acc[1], acc[2], acc[3]};
        obase[(size_t)tk * (EMBED / 4)] = o;   // 16 B/lane, 1 KB/wave, coalesced
    }
}

extern "C" void kernel_launch(void* const* d_in, const int* in_sizes, int n_in,
                              void* d_out, int out_size, void* d_ws, size_t ws_size,
                              hipStream_t stream) {
    const int*   tok   = (const int*)d_in[0];
    const float* ctab  = (const float*)d_in[1];
    const float* W     = (const float*)d_in[2];
    const float* scale = (const float*)d_in[3];
    float*       out   = (float*)d_out;

    FractalEmbedding_30365418782757_kernel<<<GRID, BLOCK, 0, stream>>>(tok, ctab, W, scale, out);
}